// Round 1
// 243.404 us; speedup vs baseline: 1.0283x; 1.0283x over previous
//
#include <hip/hip_runtime.h>
#include <cmath>

#define DIM 384
#define IMG 112
#define IMG2 (IMG*IMG)          // 12544
#define FINALN 16
#define PATCH 49
#define DROP_P 0.2f

// Fully fused: one block per output patch (b,h,w). 2048 blocks x 512 threads.
// LDS: patch (384*49 fp32 = 75.3 KB) + aw (1.5 KB) + partials (1.5 KB) = 78.3 KB
//   -> 2 blocks/CU (needs VGPR<=128, hence launch_bounds(512,4)).
// Staging is line-request bound, NOT HBM bound: old map put 64 lanes 448B apart
// (64 lines/instr). New map: 8 lanes per (c,i)-run -> lanes share lines,
// ~4.7x fewer L1 line lookups; staging drops to the HBM/L3 floor.
__global__ __launch_bounds__(512, 4) void kFused(const float* __restrict__ hr,
                                                 const float* __restrict__ du,
                                                 const float* __restrict__ aw,
                                                 const float* __restrict__ ab,
                                                 const float* __restrict__ wmat,
                                                 const float* __restrict__ bmat,
                                                 float* __restrict__ out) {
    __shared__ float sp[DIM * PATCH];   // patch, c-major: sp[c*49 + i*7 + j]
    __shared__ float s_aw[DIM];
    __shared__ float s_red[8 * PATCH];  // 392 logit partials, then 49 attn

    int tid = threadIdx.x;

    // XCD-locality swizzle: each XCD gets a contiguous stripe of patch ids so
    // w-adjacent patches (sharing 64B hr sectors) hit the same per-XCD L2.
    int id  = blockIdx.x;                 // 0..2047
    int nid = (id & 7) * 256 + (id >> 3);
    int b = nid >> 8;
    int h = (nid >> 4) & 15;
    int w = nid & 15;

    // ---- prefetch tiny scalars off the critical path (used by wave 0 later) ----
    float duv = 0.f, abv = 0.f, wv = 0.f, bv = 0.f;
    if (tid < 64) {
        if (tid < PATCH) { wv = wmat[tid]; bv = bmat[tid]; }
        duv = du[(b << 8) + (h << 4) + w];
        abv = ab[0];
    }
    for (int i = tid; i < DIM; i += 512) s_aw[i] = aw[i];

    // ---- stage patch: 8 lanes per (c,i) run of 7 floats; lanes j=0..6 active.
    //      Group g = tid>>3 owns 42 runs = channels 6g..6g+5, rows 0..6.
    //      it/7, it%7 are compile-time -> LDS offsets fold into ds_write imms;
    //      all 42 loads issue before the writes (counted vmcnt drain).
    const float* base = hr + (size_t)b * DIM * IMG2 + (size_t)(7 * h) * IMG + 7 * w;
    {
        int g = tid >> 3;                 // 0..63
        int j = tid & 7;                  // 0..7 (7 = idle lane)
        const float* gp = base + (size_t)g * 6 * IMG2 + j;
        float* lp = sp + g * 6 * PATCH + j;
        if (j < 7) {
            float v[42];
            #pragma unroll
            for (int it = 0; it < 42; ++it) {
                const int cc = it / 7, s = it % 7;          // constants
                v[it] = gp[(size_t)cc * IMG2 + s * IMG];
            }
            #pragma unroll
            for (int it = 0; it < 42; ++it) {
                const int cc = it / 7, s = it % 7;
                lp[cc * PATCH + s * 7] = v[it];
            }
        }
    }
    __syncthreads();

    // ---- logits: 8 groups x 48 channels, threads 0..391 ----
    if (tid < 8 * PATCH) {
        int g = tid / PATCH;            // 0..7
        int p = tid - g * PATCH;        // 0..48
        int c0 = g * 48;
        float acc = 0.f;
        #pragma unroll 8
        for (int c = 0; c < 48; ++c)
            acc = fmaf(sp[(c0 + c) * PATCH + p], s_aw[c0 + c], acc);
        s_red[tid] = acc;
    }
    __syncthreads();

    // ---- wave 0: finalize logits, masked affine, softmax over 49 ----
    if (tid < 64) {
        float al = -1e30f;
        if (tid < PATCH) {
            float logit = abv;
            #pragma unroll
            for (int g = 0; g < 8; ++g) logit += s_red[g * PATCH + tid];
            float mask = (duv > DROP_P) ? 1.0f : 0.0f;
            al = fmaf(logit * mask, wv, bv);
        }
        float m = al;
        #pragma unroll
        for (int d = 32; d >= 1; d >>= 1) m = fmaxf(m, __shfl_xor(m, d, 64));
        float e = (tid < PATCH) ? __expf(al - m) : 0.f;
        float s = e;
        #pragma unroll
        for (int d = 32; d >= 1; d >>= 1) s += __shfl_xor(s, d, 64);
        if (tid < PATCH) s_red[tid] = e / s;   // attn
    }
    __syncthreads();

    // ---- output: thread -> channel; sp stride-49 across lanes (odd stride =
    //      full bank permutation, conflict-free); s_red[p] broadcast ----
    if (tid < DIM) {
        const float* pc = sp + tid * PATCH;
        float acc = 0.f;
        #pragma unroll
        for (int p = 0; p < PATCH; ++p)
            acc = fmaf(pc[p], s_red[p], acc);
        out[(((size_t)b * DIM + tid) * FINALN + h) * FINALN + w] = acc;
    }
}

extern "C" void kernel_launch(void* const* d_in, const int* in_sizes, int n_in,
                              void* d_out, int out_size, void* d_ws, size_t ws_size,
                              hipStream_t stream) {
    const float* hr   = (const float*)d_in[0];
    // d_in[1] = guidance (unused by reference)
    const float* du   = (const float*)d_in[2];
    const float* aw   = (const float*)d_in[3];
    const float* ab   = (const float*)d_in[4];
    const float* wmat = (const float*)d_in[5];
    const float* bmat = (const float*)d_in[6];
    float* out = (float*)d_out;

    kFused<<<2048, 512, 0, stream>>>(hr, du, aw, ab, wmat, bmat, out);
}